// Round 3
// baseline (637.339 us; speedup 1.0000x reference)
//
#include <hip/hip_runtime.h>
#include <hip/hip_bf16.h>
#include <cstdint>
#include <cstddef>

typedef __bf16 bf16_t;
typedef __bf16 bf8_t __attribute__((ext_vector_type(8)));
typedef float f4_t __attribute__((ext_vector_type(4)));
typedef float f8_t __attribute__((ext_vector_type(8)));

#define DEV static __device__ __forceinline__

DEV f4_t mfma16(bf8_t a, bf8_t b, f4_t c) {
    return __builtin_amdgcn_mfma_f32_16x16x32_bf16(a, b, c, 0, 0, 0);
}

DEV bf8_t cvt8(f8_t v) {
    bf8_t r;
#pragma unroll
    for (int i = 0; i < 8; ++i) r[i] = (bf16_t)v[i];
    return r;
}

// C = A @ B^T.  A: [M,K] fp32 row-major.  B: [N,K] fp32 row-major (nn.Linear weight).
// Internally bf16 MFMA. MODE 0: C bf16 [M,N]. MODE 1: V-transposed bf16 [B*H][D][S].
constexpr int LDT = 40; // padded LDS row stride (elements) for 32-col tiles; 80B = 16B-aligned

template <int MODE>
__global__ __launch_bounds__(256) void gemm_bt(const float* __restrict__ A,
                                               const float* __restrict__ B,
                                               void* __restrict__ Cv,
                                               int M, int N, int K) {
    __shared__ bf16_t As[128 * LDT];
    __shared__ bf16_t Bs[128 * LDT];
    const int tid = threadIdx.x;
    const int lane = tid & 63;
    const int wave = tid >> 6;
    const int bm0 = blockIdx.y * 128;
    const int bn0 = blockIdx.x * 128;
    const int wm = (wave >> 1) * 64;
    const int wn = (wave & 1) * 64;
    const int q4 = lane >> 4;
    const int r16 = lane & 15;

    f4_t acc[4][4] = {};

    for (int k0 = 0; k0 < K; k0 += 32) {
        __syncthreads();
        // stage 128x32 fp32 -> bf16 LDS. 512 chunks of 8 elements; thread t does chunks t, t+256.
#pragma unroll
        for (int i = 0; i < 2; ++i) {
            const int c = tid + i * 256;
            const int row = c >> 2;
            const int col = (c & 3) * 8;
            const f8_t va = *(const f8_t*)&A[(size_t)(bm0 + row) * K + k0 + col];
            const f8_t vb = *(const f8_t*)&B[(size_t)(bn0 + row) * K + k0 + col];
            *(bf8_t*)&As[row * LDT + col] = cvt8(va);
            *(bf8_t*)&Bs[row * LDT + col] = cvt8(vb);
        }
        __syncthreads();

        bf8_t af[4], bfr[4];
#pragma unroll
        for (int i = 0; i < 4; ++i)
            af[i] = *(const bf8_t*)&As[(wm + i * 16 + r16) * LDT + q4 * 8];
#pragma unroll
        for (int j = 0; j < 4; ++j)
            bfr[j] = *(const bf8_t*)&Bs[(wn + j * 16 + r16) * LDT + q4 * 8];
#pragma unroll
        for (int i = 0; i < 4; ++i)
#pragma unroll
            for (int j = 0; j < 4; ++j)
                acc[i][j] = mfma16(af[i], bfr[j], acc[i][j]);
    }

    // C/D layout per 16x16 tile: row = q4*4 + reg (A/m index), col = r16 (B/n index)
#pragma unroll
    for (int i = 0; i < 4; ++i) {
#pragma unroll
        for (int j = 0; j < 4; ++j) {
#pragma unroll
            for (int r = 0; r < 4; ++r) {
                const int m = bm0 + wm + i * 16 + q4 * 4 + r;
                const int n = bn0 + wn + j * 16 + r16;
                const float v = acc[i][j][r];
                if (MODE == 0) {
                    ((bf16_t*)Cv)[(size_t)m * N + n] = (bf16_t)v;
                } else {
                    const int bb = m >> 11, s = m & 2047;
                    const int h = n >> 7, d = n & 127;
                    ((bf16_t*)Cv)[(((size_t)(bb * 16 + h) * 128 + d) << 11) + s] = (bf16_t)v;
                }
            }
        }
    }
}

// Final GEMM: A bf16 [M,K] (attention output), B fp32 weight [N,K], C fp32 [M,N].
__global__ __launch_bounds__(256) void gemm_bt_bf16A(const bf16_t* __restrict__ A,
                                                     const float* __restrict__ B,
                                                     float* __restrict__ C,
                                                     int M, int N, int K) {
    __shared__ bf16_t As[128 * LDT];
    __shared__ bf16_t Bs[128 * LDT];
    const int tid = threadIdx.x;
    const int lane = tid & 63;
    const int wave = tid >> 6;
    const int bm0 = blockIdx.y * 128;
    const int bn0 = blockIdx.x * 128;
    const int wm = (wave >> 1) * 64;
    const int wn = (wave & 1) * 64;
    const int q4 = lane >> 4;
    const int r16 = lane & 15;

    f4_t acc[4][4] = {};

    for (int k0 = 0; k0 < K; k0 += 32) {
        __syncthreads();
#pragma unroll
        for (int i = 0; i < 2; ++i) {
            const int c = tid + i * 256;
            const int row = c >> 2;
            const int col = (c & 3) * 8;
            *(bf8_t*)&As[row * LDT + col] =
                *(const bf8_t*)&A[(size_t)(bm0 + row) * K + k0 + col];
            const f8_t vb = *(const f8_t*)&B[(size_t)(bn0 + row) * K + k0 + col];
            *(bf8_t*)&Bs[row * LDT + col] = cvt8(vb);
        }
        __syncthreads();

        bf8_t af[4], bfr[4];
#pragma unroll
        for (int i = 0; i < 4; ++i)
            af[i] = *(const bf8_t*)&As[(wm + i * 16 + r16) * LDT + q4 * 8];
#pragma unroll
        for (int j = 0; j < 4; ++j)
            bfr[j] = *(const bf8_t*)&Bs[(wn + j * 16 + r16) * LDT + q4 * 8];
#pragma unroll
        for (int i = 0; i < 4; ++i)
#pragma unroll
            for (int j = 0; j < 4; ++j)
                acc[i][j] = mfma16(af[i], bfr[j], acc[i][j]);
    }

#pragma unroll
    for (int i = 0; i < 4; ++i)
#pragma unroll
        for (int j = 0; j < 4; ++j)
#pragma unroll
            for (int r = 0; r < 4; ++r) {
                const int m = bm0 + wm + i * 16 + q4 * 4 + r;
                const int n = bn0 + wn + j * 16 + r16;
                C[(size_t)m * N + n] = acc[i][j][r];
            }
}

// Flash attention. Q,K: [B*S, C] bf16 (head h at cols h*128..). VT: [B*H][D=128][S] bf16.
// O: [B*S, C] bf16. Block = (q-tile of 64 rows, b*16+h); 4 waves each own a 16-row q strip.
constexpr int LQK = 136; // 64x128 tile stride (272B, 16B-aligned)
constexpr int LV = 72;   // 128x64 tile stride (144B, 16B-aligned)

__global__ __launch_bounds__(256) void flash_attn(const bf16_t* __restrict__ Q,
                                                  const bf16_t* __restrict__ K,
                                                  const bf16_t* __restrict__ VT,
                                                  bf16_t* __restrict__ O) {
    constexpr int S = 2048, C = 2048;
    constexpr float SCL = 0.08838834764831845f * 1.4426950408889634f; // 1/sqrt(128)*log2(e)
    __shared__ bf16_t Qs[64 * LQK];
    __shared__ bf16_t Ks[64 * LQK];
    __shared__ bf16_t Vs[128 * LV]; // V^T tile: [d][kv]
    __shared__ bf16_t Ps[64 * LV];  // P tile [q][kv]

    const int tid = threadIdx.x, lane = tid & 63, wave = tid >> 6;
    const int q4 = lane >> 4, r16 = lane & 15;
    const int bh = blockIdx.y;
    const int b = bh >> 4, h = bh & 15;
    const int q0 = blockIdx.x * 64;

    const size_t headbase = (size_t)b * S * C + (size_t)h * 128;

    // stage Q tile (64x128): 1024 chunks of 8; thread does chunks tid + 256*i
#pragma unroll
    for (int i = 0; i < 4; ++i) {
        const int c = tid + i * 256;
        const int row = c >> 4;
        const int col = (c & 15) * 8;
        *(bf8_t*)&Qs[row * LQK + col] =
            *(const bf8_t*)&Q[headbase + (size_t)(q0 + row) * C + col];
    }

    f4_t o[8] = {};
    float m_i[4] = {-1e30f, -1e30f, -1e30f, -1e30f};
    float l_i[4] = {0.f, 0.f, 0.f, 0.f};

    for (int kv0 = 0; kv0 < S; kv0 += 64) {
        __syncthreads(); // prior iteration's LDS reads done (also covers initial Q writes)
#pragma unroll
        for (int i = 0; i < 4; ++i) {
            const int c = tid + i * 256;
            { // K tile 64x128
                const int row = c >> 4;
                const int col = (c & 15) * 8;
                *(bf8_t*)&Ks[row * LQK + col] =
                    *(const bf8_t*)&K[headbase + (size_t)(kv0 + row) * C + col];
            }
            { // V^T tile 128x64
                const int row = c >> 3;
                const int col = (c & 7) * 8;
                *(bf8_t*)&Vs[row * LV + col] =
                    *(const bf8_t*)&VT[((size_t)bh * 128 + row) * S + kv0 + col];
            }
        }
        __syncthreads();

        // S = Q K^T: wave strip = 16 q rows x 64 kv cols
        f4_t s4[4] = {};
        const int arow = wave * 16 + r16;
#pragma unroll
        for (int kk = 0; kk < 4; ++kk) {
            const bf8_t aq = *(const bf8_t*)&Qs[arow * LQK + (kk * 4 + q4) * 8];
#pragma unroll
            for (int j = 0; j < 4; ++j) {
                const bf8_t bk = *(const bf8_t*)&Ks[(j * 16 + r16) * LQK + (kk * 4 + q4) * 8];
                s4[j] = mfma16(aq, bk, s4[j]);
            }
        }

        // online softmax; value s4[j][r] sits at row q4*4+r (of strip), col j*16+r16
        float alpha[4];
#pragma unroll
        for (int r = 0; r < 4; ++r) {
            float ls[4];
            float mx = -1e30f;
#pragma unroll
            for (int j = 0; j < 4; ++j) {
                ls[j] = s4[j][r] * SCL;
                mx = fmaxf(mx, ls[j]);
            }
#pragma unroll
            for (int off = 1; off < 16; off <<= 1) mx = fmaxf(mx, __shfl_xor(mx, off));
            const float mn = fmaxf(m_i[r], mx);
            alpha[r] = exp2f(m_i[r] - mn);
            m_i[r] = mn;
            float sum = 0.f;
#pragma unroll
            for (int j = 0; j < 4; ++j) {
                const float p = exp2f(ls[j] - mn);
                s4[j][r] = p;
                sum += p;
            }
#pragma unroll
            for (int off = 1; off < 16; off <<= 1) sum += __shfl_xor(sum, off);
            l_i[r] = l_i[r] * alpha[r] + sum;
        }

        // P (C-layout) -> LDS as A-operand source
#pragma unroll
        for (int r = 0; r < 4; ++r) {
            const int prow = wave * 16 + q4 * 4 + r;
#pragma unroll
            for (int j = 0; j < 4; ++j) Ps[prow * LV + j * 16 + r16] = (bf16_t)s4[j][r];
        }
        __syncthreads();

        // O = O*alpha + P @ V
#pragma unroll
        for (int t = 0; t < 8; ++t)
#pragma unroll
            for (int r = 0; r < 4; ++r) o[t][r] *= alpha[r];

#pragma unroll
        for (int kk = 0; kk < 2; ++kk) {
            const bf8_t ap = *(const bf8_t*)&Ps[(wave * 16 + r16) * LV + kk * 32 + q4 * 8];
#pragma unroll
            for (int t = 0; t < 8; ++t) {
                const bf8_t bv = *(const bf8_t*)&Vs[(t * 16 + r16) * LV + (kk * 4 + q4) * 8];
                o[t] = mfma16(ap, bv, o[t]);
            }
        }
    }

    float invl[4];
#pragma unroll
    for (int r = 0; r < 4; ++r) invl[r] = 1.0f / l_i[r];
#pragma unroll
    for (int t = 0; t < 8; ++t)
#pragma unroll
        for (int r = 0; r < 4; ++r) {
            const int qrow = q0 + wave * 16 + q4 * 4 + r;
            O[(size_t)(b * S + qrow) * C + h * 128 + t * 16 + r16] = (bf16_t)(o[t][r] * invl[r]);
        }
}

extern "C" void kernel_launch(void* const* d_in, const int* in_sizes, int n_in,
                              void* d_out, int out_size, void* d_ws, size_t ws_size,
                              hipStream_t stream) {
    const float* x  = (const float*)d_in[0];
    const float* wq = (const float*)d_in[1];
    const float* wk = (const float*)d_in[2];
    const float* wv = (const float*)d_in[3];
    const float* wo = (const float*)d_in[4];

    bf16_t* ws = (bf16_t*)d_ws;
    const size_t TSZ = (size_t)4096 * 2048; // elements per intermediate buffer
    bf16_t* Qb = ws;
    bf16_t* Kb = ws + TSZ;
    bf16_t* Vt = ws + 2 * TSZ;
    bf16_t* At = ws + 3 * TSZ;

    const int M = 4096, N = 2048, Kd = 2048;
    dim3 grid(N / 128, M / 128); // (16, 32)
    gemm_bt<0><<<grid, 256, 0, stream>>>(x, wq, Qb, M, N, Kd);
    gemm_bt<0><<<grid, 256, 0, stream>>>(x, wk, Kb, M, N, Kd);
    gemm_bt<1><<<grid, 256, 0, stream>>>(x, wv, Vt, M, N, Kd);
    flash_attn<<<dim3(32, 32), 256, 0, stream>>>(Qb, Kb, Vt, At);
    gemm_bt_bf16A<<<grid, 256, 0, stream>>>(At, wo, (float*)d_out, M, N, Kd);
}